// Round 4
// baseline (2408.362 us; speedup 1.0000x reference)
//
#include <hip/hip_runtime.h>
#include <stdint.h>

#define BATCH 8192

// ---------------------------------------------------------------------------
// Stage 0: pack binarized weights + alphas
// ---------------------------------------------------------------------------
__global__ void k_pack_w2(const float* __restrict__ w2, unsigned* __restrict__ wpos,
                          unsigned* __restrict__ wneg, float* __restrict__ alpha2){
  int t = blockIdx.x*256 + threadIdx.x;
  if (t < 1250){                       // t = o*25 + k
    int o = t/25, k = t%25;
    unsigned p=0, n=0;
    for (int i=0;i<20;i++){
      float v = w2[(o*20+i)*25 + k];
      if (v > 0.f) p |= 1u<<i;
      if (v < 0.f) n |= 1u<<i;
    }
    wpos[t] = p; wneg[t] = n;
  }
  if (t < 50){
    float s = 0.f;
    for (int i=0;i<500;i++) s += fabsf(w2[t*500+i]);
    alpha2[t] = s / 500.f;
  }
}

__global__ void k_pack_w3(const float* __restrict__ w3, unsigned* __restrict__ wpos,
                          unsigned* __restrict__ wneg, float* __restrict__ alpha3){
  int t = blockIdx.x*256 + threadIdx.x;
  if (t < 12500){                      // t = j*25 + w
    int j = t/25, w = t%25;
    unsigned p=0, n=0;
    for (int bb=0;bb<32;bb++){
      float v = w3[j*800 + w*32 + bb];
      if (v > 0.f) p |= 1u<<bb;
      if (v < 0.f) n |= 1u<<bb;
    }
    wpos[t] = p; wneg[t] = n;
  }
  if (t < 500){
    float s = 0.f;
    for (int i=0;i<800;i++) s += fabsf(w3[t*800+i]);
    alpha3[t] = s / 800.f;
  }
}

// ---------------------------------------------------------------------------
// Stage 1: conv1 (fp32) — pass A: per-channel partial sums for BN stats
// 16 images/block, jobs = pooled 2x2 blocks (4 conv outputs per job)
// ---------------------------------------------------------------------------
__global__ __launch_bounds__(256) void k_conv1_stats(const float* __restrict__ x,
        const float* __restrict__ w1, float* __restrict__ part1){
  __shared__ float img[16*784];
  __shared__ float wsh[500];
  __shared__ float red[4][40];
  int tid = threadIdx.x;
  size_t base = (size_t)blockIdx.x * 16;
  for (int i=tid;i<16*784;i+=256) img[i] = x[base*784 + i];
  for (int i=tid;i<500;i+=256)    wsh[i] = w1[i];
  __syncthreads();
  float sum[20], sq[20];
#pragma unroll
  for (int c=0;c<20;c++){ sum[c]=0.f; sq[c]=0.f; }
  for (int job=tid; job<16*144; job+=256){
    int li = job/144, pp = job%144;
    int py = pp/12, px = pp%12;
    const float* ip = &img[li*784 + py*56 + px*2];
    float a[36];
#pragma unroll
    for (int r=0;r<6;r++)
#pragma unroll
      for (int cc=0;cc<6;cc++) a[r*6+cc] = ip[r*28+cc];
#pragma unroll
    for (int c=0;c<20;c++){
      float v00=0.f,v01=0.f,v10=0.f,v11=0.f;
#pragma unroll
      for (int ky=0;ky<5;ky++)
#pragma unroll
        for (int kx=0;kx<5;kx++){
          float w = wsh[c*25 + ky*5 + kx];
          v00 = fmaf(a[ky*6+kx],       w, v00);
          v01 = fmaf(a[ky*6+kx+1],     w, v01);
          v10 = fmaf(a[(ky+1)*6+kx],   w, v10);
          v11 = fmaf(a[(ky+1)*6+kx+1], w, v11);
        }
      sum[c] += (v00+v01)+(v10+v11);
      sq[c]  = fmaf(v00,v00, fmaf(v01,v01, fmaf(v10,v10, fmaf(v11,v11, sq[c]))));
    }
  }
  int lane = tid & 63, wid = tid >> 6;
#pragma unroll
  for (int c=0;c<20;c++){
    float v1 = sum[c], v2 = sq[c];
#pragma unroll
    for (int d=32; d>0; d>>=1){ v1 += __shfl_down(v1,d); v2 += __shfl_down(v2,d); }
    if (lane==0){ red[wid][c*2] = v1; red[wid][c*2+1] = v2; }
  }
  __syncthreads();
  if (tid < 40)
    part1[blockIdx.x*40 + tid] = red[0][tid]+red[1][tid]+red[2][tid]+red[3][tid];
}

__global__ void k_reduce1(const float* __restrict__ part1, const float* __restrict__ g,
                          const float* __restrict__ b, float* __restrict__ s1t1){
  int lane = threadIdx.x; // 64
  for (int c=0;c<20;c++){
    double s=0.0, q=0.0;
    for (int i=lane;i<512;i+=64){
      s += (double)part1[i*40 + c*2];
      q += (double)part1[i*40 + c*2 + 1];
    }
#pragma unroll
    for (int d=32; d>0; d>>=1){ s += __shfl_down(s,d); q += __shfl_down(q,d); }
    if (lane==0){
      double N = 8192.0*576.0;
      double mean = s/N, var = q/N - mean*mean;
      double r = 1.0/sqrt(var + 1e-5);
      double sc = (double)g[c]*r;
      s1t1[c*2]   = (float)sc;
      s1t1[c*2+1] = (float)((double)b[c] - mean*sc);
    }
  }
}

// Stage 1 pass B: conv1 again + threshold + 2x2 OR-pool + pack 20 ch bits
__global__ __launch_bounds__(256) void k_conv1_bin(const float* __restrict__ x,
        const float* __restrict__ w1, const float* __restrict__ s1t1,
        unsigned* __restrict__ mask1){
  __shared__ float img[16*784];
  __shared__ float wsh[500];
  __shared__ float st[40];
  int tid = threadIdx.x;
  size_t base = (size_t)blockIdx.x * 16;
  for (int i=tid;i<16*784;i+=256) img[i] = x[base*784 + i];
  for (int i=tid;i<500;i+=256)    wsh[i] = w1[i];
  if (tid < 40) st[tid] = s1t1[tid];
  __syncthreads();
  for (int job=tid; job<16*144; job+=256){
    int li = job/144, pp = job%144;
    int py = pp/12, px = pp%12;
    const float* ip = &img[li*784 + py*56 + px*2];
    float a[36];
#pragma unroll
    for (int r=0;r<6;r++)
#pragma unroll
      for (int cc=0;cc<6;cc++) a[r*6+cc] = ip[r*28+cc];
    unsigned word = 0;
#pragma unroll
    for (int c=0;c<20;c++){
      float v00=0.f,v01=0.f,v10=0.f,v11=0.f;
#pragma unroll
      for (int ky=0;ky<5;ky++)
#pragma unroll
        for (int kx=0;kx<5;kx++){
          float w = wsh[c*25 + ky*5 + kx];
          v00 = fmaf(a[ky*6+kx],       w, v00);
          v01 = fmaf(a[ky*6+kx+1],     w, v01);
          v10 = fmaf(a[(ky+1)*6+kx],   w, v10);
          v11 = fmaf(a[(ky+1)*6+kx+1], w, v11);
        }
      float s = st[c*2], t = st[c*2+1];
      bool bit = (fmaf(v00,s,t) > 0.f) || (fmaf(v01,s,t) > 0.f) ||
                 (fmaf(v10,s,t) > 0.f) || (fmaf(v11,s,t) > 0.f);
      if (bit) word |= 1u<<c;
    }
    mask1[(base+li)*144 + pp] = word;
  }
}

// ---------------------------------------------------------------------------
// Stage 2: binary conv2 — pass A: integer stats of S over (N,8,8) per channel
// 8 images/block; wave-uniform o => shuffle reduce then one LDS atomic
// ---------------------------------------------------------------------------
__global__ __launch_bounds__(256) void k_conv2_stats(const unsigned* __restrict__ mask1,
    const unsigned* __restrict__ wpos, const unsigned* __restrict__ wneg,
    int* __restrict__ part2){
  __shared__ unsigned m1[8*144];
  __shared__ unsigned wp[1250], wn[1250];
  __shared__ int lsum[50], lsq[50];
  int tid = threadIdx.x;
  size_t base = (size_t)blockIdx.x * 8;
  for (int i=tid;i<8*144;i+=256) m1[i] = mask1[base*144 + i];
  for (int i=tid;i<1250;i+=256){ wp[i]=wpos[i]; wn[i]=wneg[i]; }
  if (tid<50){ lsum[tid]=0; lsq[tid]=0; }
  __syncthreads();
#pragma unroll 1
  for (int it=0; it<100; ++it){
    int job = tid + it*256;           // < 25600 = 8*50*64
    int li = job / 3200;
    int r  = job % 3200;
    int o   = r >> 6;
    int pos = r & 63;
    int y2 = pos >> 3, x2 = pos & 7;
    const unsigned* mrow = &m1[li*144];
    const unsigned* po = &wp[o*25];
    const unsigned* no = &wn[o*25];
    int S = 0;
#pragma unroll
    for (int ky=0;ky<5;ky++)
#pragma unroll
      for (int kx=0;kx<5;kx++){
        unsigned m = mrow[(y2+ky)*12 + x2+kx];
        S += __popc(m & po[ky*5+kx]) - __popc(m & no[ky*5+kx]);
      }
    int rs = S, rq = S*S;
#pragma unroll
    for (int d=32; d>0; d>>=1){ rs += __shfl_down(rs,d); rq += __shfl_down(rq,d); }
    if ((tid & 63) == 0){ atomicAdd(&lsum[o], rs); atomicAdd(&lsq[o], rq); }
  }
  __syncthreads();
  if (tid < 50){
    part2[blockIdx.x*100 + tid*2]     = lsum[tid];
    part2[blockIdx.x*100 + tid*2 + 1] = lsq[tid];
  }
}

__global__ void k_reduce2(const int* __restrict__ part2, const float* __restrict__ alpha2,
                          const float* __restrict__ g, const float* __restrict__ b,
                          float* __restrict__ s2t2){
  int lane = threadIdx.x; // 64
  for (int o=0;o<50;o++){
    long long s=0, q=0;
    for (int i=lane;i<1024;i+=64){
      s += part2[i*100 + o*2];
      q += part2[i*100 + o*2 + 1];
    }
#pragma unroll
    for (int d=32; d>0; d>>=1){ s += __shfl_down(s,d); q += __shfl_down(q,d); }
    if (lane==0){
      double N = 8192.0*64.0;
      double meanS = (double)s/N, E2 = (double)q/N;
      double varS = E2 - meanS*meanS;
      double a = (double)alpha2[o];
      double mean_g = a*meanS, var_g = a*a*varS;
      double r = 1.0/sqrt(var_g + 1e-5);
      double sc = (double)g[o]*r;
      s2t2[o*2]   = (float)(sc*a);                      // applied to integer S
      s2t2[o*2+1] = (float)((double)b[o] - mean_g*sc);
    }
  }
}

// Stage 2 pass B: recompute S, threshold, 2x2 OR-pool, pack 800 bits/image
__global__ __launch_bounds__(256) void k_bin2(const unsigned* __restrict__ mask1,
    const unsigned* __restrict__ wpos, const unsigned* __restrict__ wneg,
    const float* __restrict__ s2t2, unsigned* __restrict__ mask2){
  __shared__ unsigned m1[8*144];
  __shared__ unsigned wp[1250], wn[1250];
  __shared__ float st[100];
  __shared__ unsigned lw[200];
  int tid = threadIdx.x;
  size_t base = (size_t)blockIdx.x * 8;
  for (int i=tid;i<8*144;i+=256) m1[i] = mask1[base*144 + i];
  for (int i=tid;i<1250;i+=256){ wp[i]=wpos[i]; wn[i]=wneg[i]; }
  if (tid<100) st[tid] = s2t2[tid];
  if (tid<200) lw[tid] = 0u;
  __syncthreads();
#pragma unroll 1
  for (int it=0; it<25; ++it){
    int job = tid + it*256;            // < 6400 = 8*50*16
    int li = job / 800;
    int rr = job % 800;
    int o   = rr >> 4;
    int pos = rr & 15;
    int py = pos >> 2, px = pos & 3;
    float s = st[o*2], t = st[o*2+1];
    const unsigned* mrow = &m1[li*144];
    const unsigned* po = &wp[o*25];
    const unsigned* no = &wn[o*25];
    bool bit = false;
#pragma unroll
    for (int dy=0;dy<2;dy++)
#pragma unroll
      for (int dx=0;dx<2;dx++){
        int y2 = 2*py+dy, x2 = 2*px+dx;
        int S = 0;
#pragma unroll
        for (int ky=0;ky<5;ky++)
#pragma unroll
          for (int kx=0;kx<5;kx++){
            unsigned m = mrow[(y2+ky)*12 + x2+kx];
            S += __popc(m & po[ky*5+kx]) - __popc(m & no[ky*5+kx]);
          }
        bit = bit || (fmaf((float)S, s, t) > 0.f);
      }
    int k = o*16 + pos;
    if (bit) atomicOr(&lw[li*25 + (k>>5)], 1u << (k&31));
  }
  __syncthreads();
  if (tid < 200) mask2[base*25 + tid] = lw[tid];
}

// ---------------------------------------------------------------------------
// Stage 3: binary fc1 (800 -> 500), S3 integer; lanes = images, broadcast wts
// 32 images/block; LDS-staged masks + LDS-staged output for coalesced store
// ---------------------------------------------------------------------------
__global__ __launch_bounds__(256) void k_fc1(const unsigned* __restrict__ mask2,
    const unsigned* __restrict__ wpos, const unsigned* __restrict__ wneg,
    short* __restrict__ S3){
  __shared__ unsigned m2s[32*25];
  __shared__ short s3s[32*500];
  int tid = threadIdx.x;
  size_t base = (size_t)blockIdx.x * 32;
  for (int i=tid;i<800;i+=256) m2s[i] = mask2[base*25 + i];
  __syncthreads();
  int bl = tid & 31;
  int jg = tid >> 5;   // 8 groups
  const unsigned* mrow = &m2s[bl*25];
#pragma unroll 1
  for (int j=jg; j<500; j+=8){
    const unsigned* p = &wpos[j*25];
    const unsigned* n = &wneg[j*25];
    int S = 0;
#pragma unroll
    for (int w=0;w<25;w++){
      unsigned m = mrow[w];
      S += __popc(m & p[w]) - __popc(m & n[w]);
    }
    s3s[bl*500 + j] = (short)S;
  }
  __syncthreads();
  for (int i=tid;i<32*500;i+=256) S3[base*500 + i] = s3s[i];
}

// per-feature batch stats of S3 (int, exact): 64 images/block, 128 blocks
__global__ __launch_bounds__(256) void k_stats3(const short* __restrict__ S3,
                                                int* __restrict__ part3){
  int tid = threadIdx.x;
  const short* p = &S3[(size_t)blockIdx.x * 64 * 500];
  int s0=0,q0=0,s1=0,q1=0;
  for (int b=0;b<64;b++){
    int v0 = p[b*500 + tid];
    s0 += v0; q0 += v0*v0;
    if (tid < 244){
      int v1 = p[b*500 + tid + 256];
      s1 += v1; q1 += v1*v1;
    }
  }
  part3[blockIdx.x*1000 + tid*2]     = s0;
  part3[blockIdx.x*1000 + tid*2 + 1] = q0;
  if (tid < 244){
    part3[blockIdx.x*1000 + (tid+256)*2]     = s1;
    part3[blockIdx.x*1000 + (tid+256)*2 + 1] = q1;
  }
}

__global__ void k_reduce3(const int* __restrict__ part3, const float* __restrict__ alpha3,
                          const float* __restrict__ g, const float* __restrict__ b,
                          float* __restrict__ s3t3){
  int j = blockIdx.x*256 + threadIdx.x;
  if (j >= 500) return;
  long long s=0, q=0;
  for (int i=0;i<128;i++){
    s += part3[i*1000 + j*2];
    q += part3[i*1000 + j*2 + 1];
  }
  double N = 8192.0;
  double meanS = (double)s/N, E2 = (double)q/N;
  double varS = E2 - meanS*meanS;
  double a = (double)alpha3[j];
  double mean_u = a*meanS, var_u = a*a*varS;
  double r = 1.0/sqrt(var_u + 1e-5);
  double sc = (double)g[j]*r;
  s3t3[j*2]   = (float)(sc*a);
  s3t3[j*2+1] = (float)((double)b[j] - mean_u*sc);
}

// h3 = relu(s3*S3 + t3); out = h3 @ fc2_w^T + fc2_b
__global__ __launch_bounds__(256) void k_final(const short* __restrict__ S3,
    const float* __restrict__ s3t3, const float* __restrict__ fc2w,
    const float* __restrict__ fc2b, float* __restrict__ out){
  __shared__ float w[5000];
  __shared__ float st[1000];
  __shared__ float bias[10];
  int tid = threadIdx.x;
  for (int i=tid;i<5000;i+=256) w[i] = fc2w[i];
  for (int i=tid;i<1000;i+=256) st[i] = s3t3[i];
  if (tid<10) bias[tid] = fc2b[tid];
  __syncthreads();
  int b = blockIdx.x*256 + tid;
  float acc[10];
#pragma unroll
  for (int m=0;m<10;m++) acc[m] = bias[m];
  const short* sp = &S3[(size_t)b*500];
#pragma unroll 1
  for (int j=0;j<500;j++){
    float h = fmaf((float)sp[j], st[j*2], st[j*2+1]);
    h = fmaxf(h, 0.f);
#pragma unroll
    for (int m=0;m<10;m++) acc[m] = fmaf(h, w[m*500+j], acc[m]);
  }
#pragma unroll
  for (int m=0;m<10;m++) out[(size_t)b*10 + m] = acc[m];
}

// ---------------------------------------------------------------------------
extern "C" void kernel_launch(void* const* d_in, const int* in_sizes, int n_in,
                              void* d_out, int out_size, void* d_ws, size_t ws_size,
                              hipStream_t stream){
  const float* x    = (const float*)d_in[0];
  const float* w1   = (const float*)d_in[1];
  const float* bn1g = (const float*)d_in[2];
  const float* bn1b = (const float*)d_in[3];
  const float* w2   = (const float*)d_in[4];
  const float* bn2g = (const float*)d_in[5];
  const float* bn2b = (const float*)d_in[6];
  const float* w3   = (const float*)d_in[7];
  const float* bn3g = (const float*)d_in[8];
  const float* bn3b = (const float*)d_in[9];
  const float* w4   = (const float*)d_in[10];
  const float* b4   = (const float*)d_in[11];
  float* out = (float*)d_out;
  (void)in_sizes; (void)n_in; (void)out_size; (void)ws_size;

  char* wsb = (char*)d_ws;
  size_t off = 0;
  auto alloc = [&](size_t n){ size_t o = off; off = (off + n + 255) & ~(size_t)255; return o; };
  float*    s1t1   = (float*)(wsb + alloc(40*sizeof(float)));
  float*    s2t2   = (float*)(wsb + alloc(100*sizeof(float)));
  float*    s3t3   = (float*)(wsb + alloc(1000*sizeof(float)));
  float*    alpha2 = (float*)(wsb + alloc(50*sizeof(float)));
  float*    alpha3 = (float*)(wsb + alloc(500*sizeof(float)));
  unsigned* wpos2  = (unsigned*)(wsb + alloc(1250*4));
  unsigned* wneg2  = (unsigned*)(wsb + alloc(1250*4));
  unsigned* wpos3  = (unsigned*)(wsb + alloc(12500*4));
  unsigned* wneg3  = (unsigned*)(wsb + alloc(12500*4));
  float*    part1  = (float*)(wsb + alloc(512*40*4));
  int*      part2  = (int*)(wsb + alloc(1024*100*4));
  int*      part3  = (int*)(wsb + alloc(128*1000*4));
  unsigned* mask1  = (unsigned*)(wsb + alloc((size_t)BATCH*144*4));
  unsigned* mask2  = (unsigned*)(wsb + alloc((size_t)BATCH*25*4));
  short*    S3     = (short*)(wsb + alloc((size_t)BATCH*500*2));

  hipLaunchKernelGGL(k_pack_w2,      dim3(5),     dim3(256), 0, stream, w2, wpos2, wneg2, alpha2);
  hipLaunchKernelGGL(k_pack_w3,      dim3(49),    dim3(256), 0, stream, w3, wpos3, wneg3, alpha3);
  hipLaunchKernelGGL(k_conv1_stats,  dim3(512),   dim3(256), 0, stream, x, w1, part1);
  hipLaunchKernelGGL(k_reduce1,      dim3(1),     dim3(64),  0, stream, part1, bn1g, bn1b, s1t1);
  hipLaunchKernelGGL(k_conv1_bin,    dim3(512),   dim3(256), 0, stream, x, w1, s1t1, mask1);
  hipLaunchKernelGGL(k_conv2_stats,  dim3(1024),  dim3(256), 0, stream, mask1, wpos2, wneg2, part2);
  hipLaunchKernelGGL(k_reduce2,      dim3(1),     dim3(64),  0, stream, part2, alpha2, bn2g, bn2b, s2t2);
  hipLaunchKernelGGL(k_bin2,         dim3(1024),  dim3(256), 0, stream, mask1, wpos2, wneg2, s2t2, mask2);
  hipLaunchKernelGGL(k_fc1,          dim3(256),   dim3(256), 0, stream, mask2, wpos3, wneg3, S3);
  hipLaunchKernelGGL(k_stats3,       dim3(128),   dim3(256), 0, stream, S3, part3);
  hipLaunchKernelGGL(k_reduce3,      dim3(2),     dim3(256), 0, stream, part3, alpha3, bn3g, bn3b, s3t3);
  hipLaunchKernelGGL(k_final,        dim3(32),    dim3(256), 0, stream, S3, s3t3, w4, b4, out);
}

// Round 5
// 1001.490 us; speedup vs baseline: 2.4048x; 2.4048x over previous
//
#include <hip/hip_runtime.h>
#include <stdint.h>

#define BATCH 8192

// ---------------------------------------------------------------------------
// Stage 0: pack binarized weights + alphas
// ---------------------------------------------------------------------------
__global__ void k_pack_w2(const float* __restrict__ w2, unsigned* __restrict__ wpos,
                          unsigned* __restrict__ wneg, float* __restrict__ alpha2){
  int t = blockIdx.x*256 + threadIdx.x;
  if (t < 1250){                       // t = o*25 + k
    int o = t/25, k = t%25;
    unsigned p=0, n=0;
    for (int i=0;i<20;i++){
      float v = w2[(o*20+i)*25 + k];
      if (v > 0.f) p |= 1u<<i;
      if (v < 0.f) n |= 1u<<i;
    }
    wpos[t] = p; wneg[t] = n;
  }
  if (t < 50){
    float s = 0.f;
    for (int i=0;i<500;i++) s += fabsf(w2[t*500+i]);
    alpha2[t] = s / 500.f;
  }
}

__global__ void k_pack_w3(const float* __restrict__ w3, unsigned* __restrict__ wpos,
                          unsigned* __restrict__ wneg, float* __restrict__ alpha3){
  int t = blockIdx.x*256 + threadIdx.x;
  if (t < 12500){                      // t = j*25 + w
    int j = t/25, w = t%25;
    unsigned p=0, n=0;
    for (int bb=0;bb<32;bb++){
      float v = w3[j*800 + w*32 + bb];
      if (v > 0.f) p |= 1u<<bb;
      if (v < 0.f) n |= 1u<<bb;
    }
    wpos[t] = p; wneg[t] = n;
  }
  if (t < 500){
    float s = 0.f;
    for (int i=0;i<800;i++) s += fabsf(w3[t*800+i]);
    alpha3[t] = s / 800.f;
  }
}

// ---------------------------------------------------------------------------
// Stage 1: conv1 (fp32). 8 images/block, grid 1024. Channel-PAIR outer loop
// (weights in registers), pooled-2x2 jobs inner. ~120 VGPR, no spill.
// ---------------------------------------------------------------------------

// pass A: per-channel partial sums for BN stats (deterministic per-wave slots)
__global__ __launch_bounds__(256) void k_conv1_stats(const float* __restrict__ x,
        const float* __restrict__ w1, float* __restrict__ part1){
  __shared__ float img[8*784];
  __shared__ float wsh[500];
  __shared__ float red[4][40];
  int tid = threadIdx.x;
  size_t base = (size_t)blockIdx.x * 8;
  const float4* xv = (const float4*)(x + base*784);
  float4* iv = (float4*)img;
  for (int i=tid;i<1568;i+=256) iv[i] = xv[i];
  for (int i=tid;i<500;i+=256)  wsh[i] = w1[i];
  __syncthreads();
  int lane = tid & 63, wid = tid >> 6;
#pragma unroll 1
  for (int cg=0; cg<10; ++cg){
    float wa[25], wb[25];
#pragma unroll
    for (int k=0;k<25;k++){ wa[k]=wsh[(2*cg)*25+k]; wb[k]=wsh[(2*cg+1)*25+k]; }
    float sa=0.f, qa=0.f, sb=0.f, qb=0.f;
#pragma unroll 1
    for (int job=tid; job<8*144; job+=256){
      int li = job/144, pp = job%144;
      int py = pp/12, px = pp%12;
      const float* ip = &img[li*784 + py*56 + px*2];
      float a[36];
#pragma unroll
      for (int r=0;r<6;r++){
        const float2* rp = (const float2*)(ip + r*28);
        float2 p0 = rp[0], p1 = rp[1], p2 = rp[2];
        a[r*6+0]=p0.x; a[r*6+1]=p0.y; a[r*6+2]=p1.x;
        a[r*6+3]=p1.y; a[r*6+4]=p2.x; a[r*6+5]=p2.y;
      }
      float vA0=0.f,vA1=0.f,vA2=0.f,vA3=0.f;
      float vB0=0.f,vB1=0.f,vB2=0.f,vB3=0.f;
#pragma unroll
      for (int ky=0;ky<5;ky++)
#pragma unroll
        for (int kx=0;kx<5;kx++){
          float e00=a[ky*6+kx], e01=a[ky*6+kx+1], e10=a[ky*6+kx+6], e11=a[ky*6+kx+7];
          float w = wa[ky*5+kx];
          vA0=fmaf(e00,w,vA0); vA1=fmaf(e01,w,vA1); vA2=fmaf(e10,w,vA2); vA3=fmaf(e11,w,vA3);
          float u = wb[ky*5+kx];
          vB0=fmaf(e00,u,vB0); vB1=fmaf(e01,u,vB1); vB2=fmaf(e10,u,vB2); vB3=fmaf(e11,u,vB3);
        }
      sa += (vA0+vA1)+(vA2+vA3);
      qa = fmaf(vA0,vA0, fmaf(vA1,vA1, fmaf(vA2,vA2, fmaf(vA3,vA3, qa))));
      sb += (vB0+vB1)+(vB2+vB3);
      qb = fmaf(vB0,vB0, fmaf(vB1,vB1, fmaf(vB2,vB2, fmaf(vB3,vB3, qb))));
    }
#pragma unroll
    for (int d=32; d>0; d>>=1){
      sa += __shfl_down(sa,d); qa += __shfl_down(qa,d);
      sb += __shfl_down(sb,d); qb += __shfl_down(qb,d);
    }
    if (lane==0){
      red[wid][(2*cg)*2]   = sa; red[wid][(2*cg)*2+1]   = qa;
      red[wid][(2*cg+1)*2] = sb; red[wid][(2*cg+1)*2+1] = qb;
    }
  }
  __syncthreads();
  if (tid < 40)
    part1[blockIdx.x*40 + tid] = red[0][tid]+red[1][tid]+red[2][tid]+red[3][tid];
}

__global__ void k_reduce1(const float* __restrict__ part1, const float* __restrict__ g,
                          const float* __restrict__ b, float* __restrict__ s1t1){
  int lane = threadIdx.x; // 64
  for (int c=0;c<20;c++){
    double s=0.0, q=0.0;
    for (int i=lane;i<1024;i+=64){
      s += (double)part1[i*40 + c*2];
      q += (double)part1[i*40 + c*2 + 1];
    }
#pragma unroll
    for (int d=32; d>0; d>>=1){ s += __shfl_down(s,d); q += __shfl_down(q,d); }
    if (lane==0){
      double N = 8192.0*576.0;
      double mean = s/N, var = q/N - mean*mean;
      double r = 1.0/sqrt(var + 1e-5);
      double sc = (double)g[c]*r;
      s1t1[c*2]   = (float)sc;
      s1t1[c*2+1] = (float)((double)b[c] - mean*sc);
    }
  }
}

// pass B: conv1 + threshold + 2x2 OR-pool + pack 20 ch bits
__global__ __launch_bounds__(256) void k_conv1_bin(const float* __restrict__ x,
        const float* __restrict__ w1, const float* __restrict__ s1t1,
        unsigned* __restrict__ mask1){
  __shared__ float img[8*784];
  __shared__ float wsh[500];
  __shared__ float st[40];
  int tid = threadIdx.x;
  size_t base = (size_t)blockIdx.x * 8;
  const float4* xv = (const float4*)(x + base*784);
  float4* iv = (float4*)img;
  for (int i=tid;i<1568;i+=256) iv[i] = xv[i];
  for (int i=tid;i<500;i+=256)  wsh[i] = w1[i];
  if (tid < 40) st[tid] = s1t1[tid];
  __syncthreads();
  unsigned wbits0=0, wbits1=0, wbits2=0, wbits3=0, wbits4=0;
#pragma unroll 1
  for (int cg=0; cg<10; ++cg){
    float wa[25], wb[25];
#pragma unroll
    for (int k=0;k<25;k++){ wa[k]=wsh[(2*cg)*25+k]; wb[k]=wsh[(2*cg+1)*25+k]; }
    float sA = st[(2*cg)*2],   tA = st[(2*cg)*2+1];
    float sB = st[(2*cg+1)*2], tB = st[(2*cg+1)*2+1];
#pragma unroll
    for (int it=0; it<5; ++it){
      int job = tid + it*256;
      if (job < 8*144){
        int li = job/144, pp = job%144;
        int py = pp/12, px = pp%12;
        const float* ip = &img[li*784 + py*56 + px*2];
        float a[36];
#pragma unroll
        for (int r=0;r<6;r++){
          const float2* rp = (const float2*)(ip + r*28);
          float2 p0 = rp[0], p1 = rp[1], p2 = rp[2];
          a[r*6+0]=p0.x; a[r*6+1]=p0.y; a[r*6+2]=p1.x;
          a[r*6+3]=p1.y; a[r*6+4]=p2.x; a[r*6+5]=p2.y;
        }
        float vA0=0.f,vA1=0.f,vA2=0.f,vA3=0.f;
        float vB0=0.f,vB1=0.f,vB2=0.f,vB3=0.f;
#pragma unroll
        for (int ky=0;ky<5;ky++)
#pragma unroll
          for (int kx=0;kx<5;kx++){
            float e00=a[ky*6+kx], e01=a[ky*6+kx+1], e10=a[ky*6+kx+6], e11=a[ky*6+kx+7];
            float w = wa[ky*5+kx];
            vA0=fmaf(e00,w,vA0); vA1=fmaf(e01,w,vA1); vA2=fmaf(e10,w,vA2); vA3=fmaf(e11,w,vA3);
            float u = wb[ky*5+kx];
            vB0=fmaf(e00,u,vB0); vB1=fmaf(e01,u,vB1); vB2=fmaf(e10,u,vB2); vB3=fmaf(e11,u,vB3);
          }
        unsigned bA = (fmaf(vA0,sA,tA) > 0.f) || (fmaf(vA1,sA,tA) > 0.f) ||
                      (fmaf(vA2,sA,tA) > 0.f) || (fmaf(vA3,sA,tA) > 0.f);
        unsigned bB = (fmaf(vB0,sB,tB) > 0.f) || (fmaf(vB1,sB,tB) > 0.f) ||
                      (fmaf(vB2,sB,tB) > 0.f) || (fmaf(vB3,sB,tB) > 0.f);
        unsigned add = (bA << (2*cg)) | (bB << (2*cg+1));
        if (it==0) wbits0 |= add;
        else if (it==1) wbits1 |= add;
        else if (it==2) wbits2 |= add;
        else if (it==3) wbits3 |= add;
        else wbits4 |= add;
      }
    }
  }
#pragma unroll
  for (int it=0; it<5; ++it){
    int job = tid + it*256;
    if (job < 8*144){
      int li = job/144, pp = job%144;
      unsigned w = (it==0)?wbits0:(it==1)?wbits1:(it==2)?wbits2:(it==3)?wbits3:wbits4;
      mask1[(base+li)*144 + pp] = w;
    }
  }
}

// ---------------------------------------------------------------------------
// Stage 2: binary conv2 — pass A: integer stats of S over (N,8,8) per channel
// 8 images/block; wave-uniform o => shuffle reduce then one LDS atomic
// ---------------------------------------------------------------------------
__global__ __launch_bounds__(256) void k_conv2_stats(const unsigned* __restrict__ mask1,
    const unsigned* __restrict__ wpos, const unsigned* __restrict__ wneg,
    int* __restrict__ part2){
  __shared__ unsigned m1[8*144];
  __shared__ unsigned wp[1250], wn[1250];
  __shared__ int lsum[50], lsq[50];
  int tid = threadIdx.x;
  size_t base = (size_t)blockIdx.x * 8;
  for (int i=tid;i<8*144;i+=256) m1[i] = mask1[base*144 + i];
  for (int i=tid;i<1250;i+=256){ wp[i]=wpos[i]; wn[i]=wneg[i]; }
  if (tid<50){ lsum[tid]=0; lsq[tid]=0; }
  __syncthreads();
#pragma unroll 1
  for (int it=0; it<100; ++it){
    int job = tid + it*256;           // < 25600 = 8*50*64
    int li = job / 3200;
    int r  = job % 3200;
    int o   = r >> 6;
    int pos = r & 63;
    int y2 = pos >> 3, x2 = pos & 7;
    const unsigned* mrow = &m1[li*144];
    const unsigned* po = &wp[o*25];
    const unsigned* no = &wn[o*25];
    int S = 0;
#pragma unroll
    for (int ky=0;ky<5;ky++)
#pragma unroll
      for (int kx=0;kx<5;kx++){
        unsigned m = mrow[(y2+ky)*12 + x2+kx];
        S += __popc(m & po[ky*5+kx]) - __popc(m & no[ky*5+kx]);
      }
    int rs = S, rq = S*S;
#pragma unroll
    for (int d=32; d>0; d>>=1){ rs += __shfl_down(rs,d); rq += __shfl_down(rq,d); }
    if ((tid & 63) == 0){ atomicAdd(&lsum[o], rs); atomicAdd(&lsq[o], rq); }
  }
  __syncthreads();
  if (tid < 50){
    part2[blockIdx.x*100 + tid*2]     = lsum[tid];
    part2[blockIdx.x*100 + tid*2 + 1] = lsq[tid];
  }
}

__global__ void k_reduce2(const int* __restrict__ part2, const float* __restrict__ alpha2,
                          const float* __restrict__ g, const float* __restrict__ b,
                          float* __restrict__ s2t2){
  int lane = threadIdx.x; // 64
  for (int o=0;o<50;o++){
    long long s=0, q=0;
    for (int i=lane;i<1024;i+=64){
      s += part2[i*100 + o*2];
      q += part2[i*100 + o*2 + 1];
    }
#pragma unroll
    for (int d=32; d>0; d>>=1){ s += __shfl_down(s,d); q += __shfl_down(q,d); }
    if (lane==0){
      double N = 8192.0*64.0;
      double meanS = (double)s/N, E2 = (double)q/N;
      double varS = E2 - meanS*meanS;
      double a = (double)alpha2[o];
      double mean_g = a*meanS, var_g = a*a*varS;
      double r = 1.0/sqrt(var_g + 1e-5);
      double sc = (double)g[o]*r;
      s2t2[o*2]   = (float)(sc*a);                      // applied to integer S
      s2t2[o*2+1] = (float)((double)b[o] - mean_g*sc);
    }
  }
}

// Stage 2 pass B: recompute S, threshold, 2x2 OR-pool, pack 800 bits/image
__global__ __launch_bounds__(256) void k_bin2(const unsigned* __restrict__ mask1,
    const unsigned* __restrict__ wpos, const unsigned* __restrict__ wneg,
    const float* __restrict__ s2t2, unsigned* __restrict__ mask2){
  __shared__ unsigned m1[8*144];
  __shared__ unsigned wp[1250], wn[1250];
  __shared__ float st[100];
  __shared__ unsigned lw[200];
  int tid = threadIdx.x;
  size_t base = (size_t)blockIdx.x * 8;
  for (int i=tid;i<8*144;i+=256) m1[i] = mask1[base*144 + i];
  for (int i=tid;i<1250;i+=256){ wp[i]=wpos[i]; wn[i]=wneg[i]; }
  if (tid<100) st[tid] = s2t2[tid];
  if (tid<200) lw[tid] = 0u;
  __syncthreads();
#pragma unroll 1
  for (int it=0; it<25; ++it){
    int job = tid + it*256;            // < 6400 = 8*50*16
    int li = job / 800;
    int rr = job % 800;
    int o   = rr >> 4;
    int pos = rr & 15;
    int py = pos >> 2, px = pos & 3;
    float s = st[o*2], t = st[o*2+1];
    const unsigned* mrow = &m1[li*144];
    const unsigned* po = &wp[o*25];
    const unsigned* no = &wn[o*25];
    bool bit = false;
#pragma unroll
    for (int dy=0;dy<2;dy++)
#pragma unroll
      for (int dx=0;dx<2;dx++){
        int y2 = 2*py+dy, x2 = 2*px+dx;
        int S = 0;
#pragma unroll
        for (int ky=0;ky<5;ky++)
#pragma unroll
          for (int kx=0;kx<5;kx++){
            unsigned m = mrow[(y2+ky)*12 + x2+kx];
            S += __popc(m & po[ky*5+kx]) - __popc(m & no[ky*5+kx]);
          }
        bit = bit || (fmaf((float)S, s, t) > 0.f);
      }
    int k = o*16 + pos;
    if (bit) atomicOr(&lw[li*25 + (k>>5)], 1u << (k&31));
  }
  __syncthreads();
  if (tid < 200) mask2[base*25 + tid] = lw[tid];
}

// ---------------------------------------------------------------------------
// Stage 3: binary fc1 (800 -> 500), S3 integer; lanes = images, broadcast wts
// 32 images/block; LDS-staged masks + LDS-staged output for coalesced store
// ---------------------------------------------------------------------------
__global__ __launch_bounds__(256) void k_fc1(const unsigned* __restrict__ mask2,
    const unsigned* __restrict__ wpos, const unsigned* __restrict__ wneg,
    short* __restrict__ S3){
  __shared__ unsigned m2s[32*25];
  __shared__ short s3s[32*500];
  int tid = threadIdx.x;
  size_t base = (size_t)blockIdx.x * 32;
  for (int i=tid;i<800;i+=256) m2s[i] = mask2[base*25 + i];
  __syncthreads();
  int bl = tid & 31;
  int jg = tid >> 5;   // 8 groups
  const unsigned* mrow = &m2s[bl*25];
#pragma unroll 1
  for (int j=jg; j<500; j+=8){
    const unsigned* p = &wpos[j*25];
    const unsigned* n = &wneg[j*25];
    int S = 0;
#pragma unroll
    for (int w=0;w<25;w++){
      unsigned m = mrow[w];
      S += __popc(m & p[w]) - __popc(m & n[w]);
    }
    s3s[bl*500 + j] = (short)S;
  }
  __syncthreads();
  for (int i=tid;i<32*500;i+=256) S3[base*500 + i] = s3s[i];
}

// per-feature batch stats of S3 (int, exact): 64 images/block, 128 blocks
__global__ __launch_bounds__(256) void k_stats3(const short* __restrict__ S3,
                                                int* __restrict__ part3){
  int tid = threadIdx.x;
  const short* p = &S3[(size_t)blockIdx.x * 64 * 500];
  int s0=0,q0=0,s1=0,q1=0;
  for (int b=0;b<64;b++){
    int v0 = p[b*500 + tid];
    s0 += v0; q0 += v0*v0;
    if (tid < 244){
      int v1 = p[b*500 + tid + 256];
      s1 += v1; q1 += v1*v1;
    }
  }
  part3[blockIdx.x*1000 + tid*2]     = s0;
  part3[blockIdx.x*1000 + tid*2 + 1] = q0;
  if (tid < 244){
    part3[blockIdx.x*1000 + (tid+256)*2]     = s1;
    part3[blockIdx.x*1000 + (tid+256)*2 + 1] = q1;
  }
}

__global__ void k_reduce3(const int* __restrict__ part3, const float* __restrict__ alpha3,
                          const float* __restrict__ g, const float* __restrict__ b,
                          float* __restrict__ s3t3){
  int j = blockIdx.x*256 + threadIdx.x;
  if (j >= 500) return;
  long long s=0, q=0;
  for (int i=0;i<128;i++){
    s += part3[i*1000 + j*2];
    q += part3[i*1000 + j*2 + 1];
  }
  double N = 8192.0;
  double meanS = (double)s/N, E2 = (double)q/N;
  double varS = E2 - meanS*meanS;
  double a = (double)alpha3[j];
  double mean_u = a*meanS, var_u = a*a*varS;
  double r = 1.0/sqrt(var_u + 1e-5);
  double sc = (double)g[j]*r;
  s3t3[j*2]   = (float)(sc*a);
  s3t3[j*2+1] = (float)((double)b[j] - mean_u*sc);
}

// h3 = relu(s3*S3 + t3); out = h3 @ fc2_w^T + fc2_b
__global__ __launch_bounds__(256) void k_final(const short* __restrict__ S3,
    const float* __restrict__ s3t3, const float* __restrict__ fc2w,
    const float* __restrict__ fc2b, float* __restrict__ out){
  __shared__ float w[5000];
  __shared__ float st[1000];
  __shared__ float bias[10];
  int tid = threadIdx.x;
  for (int i=tid;i<5000;i+=256) w[i] = fc2w[i];
  for (int i=tid;i<1000;i+=256) st[i] = s3t3[i];
  if (tid<10) bias[tid] = fc2b[tid];
  __syncthreads();
  int b = blockIdx.x*256 + tid;
  float acc[10];
#pragma unroll
  for (int m=0;m<10;m++) acc[m] = bias[m];
  const short* sp = &S3[(size_t)b*500];
#pragma unroll 1
  for (int j=0;j<500;j++){
    float h = fmaf((float)sp[j], st[j*2], st[j*2+1]);
    h = fmaxf(h, 0.f);
#pragma unroll
    for (int m=0;m<10;m++) acc[m] = fmaf(h, w[m*500+j], acc[m]);
  }
#pragma unroll
  for (int m=0;m<10;m++) out[(size_t)b*10 + m] = acc[m];
}

// ---------------------------------------------------------------------------
extern "C" void kernel_launch(void* const* d_in, const int* in_sizes, int n_in,
                              void* d_out, int out_size, void* d_ws, size_t ws_size,
                              hipStream_t stream){
  const float* x    = (const float*)d_in[0];
  const float* w1   = (const float*)d_in[1];
  const float* bn1g = (const float*)d_in[2];
  const float* bn1b = (const float*)d_in[3];
  const float* w2   = (const float*)d_in[4];
  const float* bn2g = (const float*)d_in[5];
  const float* bn2b = (const float*)d_in[6];
  const float* w3   = (const float*)d_in[7];
  const float* bn3g = (const float*)d_in[8];
  const float* bn3b = (const float*)d_in[9];
  const float* w4   = (const float*)d_in[10];
  const float* b4   = (const float*)d_in[11];
  float* out = (float*)d_out;
  (void)in_sizes; (void)n_in; (void)out_size; (void)ws_size;

  char* wsb = (char*)d_ws;
  size_t off = 0;
  auto alloc = [&](size_t n){ size_t o = off; off = (off + n + 255) & ~(size_t)255; return o; };
  float*    s1t1   = (float*)(wsb + alloc(40*sizeof(float)));
  float*    s2t2   = (float*)(wsb + alloc(100*sizeof(float)));
  float*    s3t3   = (float*)(wsb + alloc(1000*sizeof(float)));
  float*    alpha2 = (float*)(wsb + alloc(50*sizeof(float)));
  float*    alpha3 = (float*)(wsb + alloc(500*sizeof(float)));
  unsigned* wpos2  = (unsigned*)(wsb + alloc(1250*4));
  unsigned* wneg2  = (unsigned*)(wsb + alloc(1250*4));
  unsigned* wpos3  = (unsigned*)(wsb + alloc(12500*4));
  unsigned* wneg3  = (unsigned*)(wsb + alloc(12500*4));
  float*    part1  = (float*)(wsb + alloc(1024*40*4));
  int*      part2  = (int*)(wsb + alloc(1024*100*4));
  int*      part3  = (int*)(wsb + alloc(128*1000*4));
  unsigned* mask1  = (unsigned*)(wsb + alloc((size_t)BATCH*144*4));
  unsigned* mask2  = (unsigned*)(wsb + alloc((size_t)BATCH*25*4));
  short*    S3     = (short*)(wsb + alloc((size_t)BATCH*500*2));

  hipLaunchKernelGGL(k_pack_w2,      dim3(5),     dim3(256), 0, stream, w2, wpos2, wneg2, alpha2);
  hipLaunchKernelGGL(k_pack_w3,      dim3(49),    dim3(256), 0, stream, w3, wpos3, wneg3, alpha3);
  hipLaunchKernelGGL(k_conv1_stats,  dim3(1024),  dim3(256), 0, stream, x, w1, part1);
  hipLaunchKernelGGL(k_reduce1,      dim3(1),     dim3(64),  0, stream, part1, bn1g, bn1b, s1t1);
  hipLaunchKernelGGL(k_conv1_bin,    dim3(1024),  dim3(256), 0, stream, x, w1, s1t1, mask1);
  hipLaunchKernelGGL(k_conv2_stats,  dim3(1024),  dim3(256), 0, stream, mask1, wpos2, wneg2, part2);
  hipLaunchKernelGGL(k_reduce2,      dim3(1),     dim3(64),  0, stream, part2, alpha2, bn2g, bn2b, s2t2);
  hipLaunchKernelGGL(k_bin2,         dim3(1024),  dim3(256), 0, stream, mask1, wpos2, wneg2, s2t2, mask2);
  hipLaunchKernelGGL(k_fc1,          dim3(256),   dim3(256), 0, stream, mask2, wpos3, wneg3, S3);
  hipLaunchKernelGGL(k_stats3,       dim3(128),   dim3(256), 0, stream, S3, part3);
  hipLaunchKernelGGL(k_reduce3,      dim3(2),     dim3(256), 0, stream, part3, alpha3, bn3g, bn3b, s3t3);
  hipLaunchKernelGGL(k_final,        dim3(32),    dim3(256), 0, stream, S3, s3t3, w4, b4, out);
}